// Round 9
// baseline (87.389 us; speedup 1.0000x reference)
//
#include <hip/hip_runtime.h>

// ConvTranspose4d: temporal valid conv (KT=3) of ConvTranspose3d(stride 2, pad 1, k=3).
// Gather form: out[co,f,od,oh,ow] = sum_{i,ci,kd,kh,kw} x[ci,f+i,id,ih,iw] * W[ci,co,i,kd,kh,kw]
//   id=(od+1-kd)/2 valid iff parity matches; all parity-valid taps in range (24->47, 48->95).
// R9 = R8 + TWO FRAMES per thread (f0 and f0+3): same weight s_loads feed 2x the FMAs.
//   Theory: shared per-CU scalar pipe is the bottleneck (~9.4M total s_loads, ~37K/CU);
//   R8 proved TLP is not the limiter (2x residency, zero delta). R9 halves total
//   s_loads at constant FMA/VMEM totals -> clean test of the scalar-throughput theory.
//   acc 32->64 VGPR (est ~95 total); R8 proved >=4 waves/SIMD is enough.

typedef float f4u __attribute__((ext_vector_type(4), aligned(4)));  // unaligned-ok out vec
typedef float f4a __attribute__((ext_vector_type(4)));              // 16B-aligned
typedef float f2a __attribute__((ext_vector_type(2)));              // 8B-aligned

namespace {
constexpr int T_ = 8, D_ = 24, H_ = 48, W_ = 48;
constexpr int TO = 6, DO_ = 47, HO = 95, WO = 95;
constexpr int XCS = T_ * D_ * H_ * W_;
constexpr int XFS = D_ * H_ * W_;
constexpr int XDS = H_ * W_;
constexpr long OCS = (long)TO * DO_ * HO * WO;
constexpr int OFS = DO_ * HO * WO;
constexpr int ODS = HO * WO;

// Work-id L segments; each L covers f0 AND f0+3 (f0 in 0..2).
// S0 = od odd & oh odd (12 taps, NOW=4): 6 ohb * 23 dd * 3 f0 = 414
// S1 = od odd & oh even (6 taps, NOW=8): 3 * 23 * 3 = 207
// S2 = od even & oh odd (6 taps, NOW=8): 3 * 24 * 3 = 216
// S3 = od even & oh even (3 taps, NOW=8): 216.  L-range 1053; grid = 2*1053 (co halves).
constexpr int S0_END = 414, S1_END = 621, S2_END = 837, NWG = 2 * 1053;

template<int ND, int NH, int NOW>
__device__ __forceinline__ void conv_body(
    const float* __restrict__ x, const float* __restrict__ w,
    float* __restrict__ out, int f0, int od, int oh, int t, int cob)
{
  const int iwb = (NOW == 8 ? 4 : 2) * t;
  const int TMAX = (NOW == 8) ? 11 : 23;
  const int xext = (t < TMAX) ? (NOW / 2) : 0;  // clamp: extra elem feeds only discarded ow=95

  float acc[2][4][NOW];                          // [frame][co][m]
  #pragma unroll
  for (int fr = 0; fr < 2; ++fr)
    #pragma unroll
    for (int co = 0; co < 4; ++co)
      #pragma unroll
      for (int m = 0; m < NOW; ++m) acc[fr][co][m] = 0.f;

  #pragma unroll 1
  for (int ci = 0; ci < 8; ++ci) {
    // SGPR base (ci*648 + co-half*81); all offsets below are compile-time immediates.
    const float* pw = w + __builtin_amdgcn_readfirstlane(ci * 648 + cob * 81);
    const float* pxc = x + ci * XCS + iwb;
    #pragma unroll
    for (int i = 0; i < 3; ++i) {
      #pragma unroll
      for (int a = 0; a < ND; ++a) {
        const int KD = (ND == 1) ? 1 : (a == 0 ? 0 : 2);
        const int id = (ND == 1) ? (od >> 1) : (a == 0 ? ((od + 1) >> 1) : ((od - 1) >> 1));
        #pragma unroll
        for (int b = 0; b < NH; ++b) {
          const int KH = (NH == 1) ? 1 : (b == 0 ? 0 : 2);
          const int ih = (NH == 1) ? (oh >> 1) : (b == 0 ? ((oh + 1) >> 1) : ((oh - 1) >> 1));
          const int WOFF = i * 27 + KD * 9 + KH * 3;   // compile-time
          const float* px0 = pxc + (f0 + i) * XFS + id * XDS + ih * W_;
          const float* px1 = px0 + 3 * XFS;            // frame f0+3
          if (NOW == 8) {
            const f4a xa0 = *(const f4a*)px0;          // 16B aligned
            const float xb0 = px0[xext];
            const f4a xa1 = *(const f4a*)px1;
            const float xb1 = px1[xext];
            #pragma unroll
            for (int co = 0; co < 4; ++co) {
              const float w0 = pw[co * 81 + WOFF + 0];
              const float w1 = pw[co * 81 + WOFF + 1];
              const float w2 = pw[co * 81 + WOFF + 2];
              acc[0][co][0] = fmaf(xa0.x, w1, acc[0][co][0]);
              acc[0][co][2] = fmaf(xa0.y, w1, acc[0][co][2]);
              acc[0][co][4] = fmaf(xa0.z, w1, acc[0][co][4]);
              acc[0][co][6] = fmaf(xa0.w, w1, acc[0][co][6]);
              acc[0][co][1] = fmaf(xa0.y, w0, fmaf(xa0.x, w2, acc[0][co][1]));
              acc[0][co][3] = fmaf(xa0.z, w0, fmaf(xa0.y, w2, acc[0][co][3]));
              acc[0][co][5] = fmaf(xa0.w, w0, fmaf(xa0.z, w2, acc[0][co][5]));
              acc[0][co][7] = fmaf(xb0,   w0, fmaf(xa0.w, w2, acc[0][co][7]));
              acc[1][co][0] = fmaf(xa1.x, w1, acc[1][co][0]);
              acc[1][co][2] = fmaf(xa1.y, w1, acc[1][co][2]);
              acc[1][co][4] = fmaf(xa1.z, w1, acc[1][co][4]);
              acc[1][co][6] = fmaf(xa1.w, w1, acc[1][co][6]);
              acc[1][co][1] = fmaf(xa1.y, w0, fmaf(xa1.x, w2, acc[1][co][1]));
              acc[1][co][3] = fmaf(xa1.z, w0, fmaf(xa1.y, w2, acc[1][co][3]));
              acc[1][co][5] = fmaf(xa1.w, w0, fmaf(xa1.z, w2, acc[1][co][5]));
              acc[1][co][7] = fmaf(xb1,   w0, fmaf(xa1.w, w2, acc[1][co][7]));
            }
          } else {
            const f2a xa0 = *(const f2a*)px0;          // 8B aligned
            const float x00 = xa0.x, x01 = xa0.y;
            const float xb0 = px0[xext];
            const f2a xa1 = *(const f2a*)px1;
            const float x10 = xa1.x, x11 = xa1.y;
            const float xb1 = px1[xext];
            #pragma unroll
            for (int co = 0; co < 4; ++co) {
              const float w0 = pw[co * 81 + WOFF + 0];
              const float w1 = pw[co * 81 + WOFF + 1];
              const float w2 = pw[co * 81 + WOFF + 2];
              acc[0][co][0] = fmaf(x00, w1, acc[0][co][0]);
              acc[0][co][2] = fmaf(x01, w1, acc[0][co][2]);
              acc[0][co][1] = fmaf(x01, w0, fmaf(x00, w2, acc[0][co][1]));
              acc[0][co][3] = fmaf(xb0, w0, fmaf(x01, w2, acc[0][co][3]));
              acc[1][co][0] = fmaf(x10, w1, acc[1][co][0]);
              acc[1][co][2] = fmaf(x11, w1, acc[1][co][2]);
              acc[1][co][1] = fmaf(x11, w0, fmaf(x10, w2, acc[1][co][1]));
              acc[1][co][3] = fmaf(xb1, w0, fmaf(x11, w2, acc[1][co][3]));
            }
          }
        }
      }
    }
  }

  #pragma unroll
  for (int fr = 0; fr < 2; ++fr) {
    const long ob = (long)(f0 + 3 * fr) * OFS + (long)od * ODS + (long)oh * HO + NOW * t;
    #pragma unroll
    for (int co = 0; co < 4; ++co) {
      float* po = out + (long)(cob + co) * OCS + ob;
      if (NOW == 8) {
        f4u lo; lo.x = acc[fr][co][0]; lo.y = acc[fr][co][1];
        lo.z = acc[fr][co][2]; lo.w = acc[fr][co][3];
        *(f4u*)po = lo;
        if (t < 11) {
          f4u hi; hi.x = acc[fr][co][4]; hi.y = acc[fr][co][5];
          hi.z = acc[fr][co][6]; hi.w = acc[fr][co][7];
          *(f4u*)(po + 4) = hi;
        } else {                       // ow = 88..94 (ow=95 doesn't exist)
          po[4] = acc[fr][co][4]; po[5] = acc[fr][co][5]; po[6] = acc[fr][co][6];
        }
      } else {
        if (t < 23) {
          f4u v; v.x = acc[fr][co][0]; v.y = acc[fr][co][1];
          v.z = acc[fr][co][2]; v.w = acc[fr][co][3];
          *(f4u*)po = v;
        } else {                       // ow = 92..94 (ow=95 doesn't exist)
          po[0] = acc[fr][co][0]; po[1] = acc[fr][co][1]; po[2] = acc[fr][co][2];
        }
      }
    }
  }
}

__global__ __launch_bounds__(192) void convt4d_kernel(
    const float* __restrict__ x, const float* __restrict__ w,
    float* __restrict__ out)
{
  const int tid = threadIdx.x;
  const int cob = (blockIdx.x & 1) * 4;        // co half: {0..3} or {4..7}
  const int L = blockIdx.x >> 1;               // work id
  if (L < S0_END) {                            // od odd, oh odd: NOW=4
    const int ohb = L % 6; const int rest = L / 6;
    const int dd = rest % 23; const int f0 = rest / 23;
    const int od = 2 * dd + 1;
    const int t = tid % 24, yy = tid / 24;     // 24 ow-groups x 8 rows
    const int row = ohb * 8 + yy; if (row >= 47) return;
    const int oh = 2 * row + 1;
    conv_body<2, 2, 4>(x, w, out, f0, od, oh, t, cob);
  } else if (L < S1_END) {                     // od odd, oh even
    const int b2 = L - S0_END;
    const int ohb = b2 % 3; const int rest = b2 / 3;
    const int dd = rest % 23; const int f0 = rest / 23;
    const int od = 2 * dd + 1;
    const int t = tid % 12, yy = tid / 12;
    const int oh = 2 * (ohb * 16 + yy);
    conv_body<2, 1, 8>(x, w, out, f0, od, oh, t, cob);
  } else if (L < S2_END) {                     // od even, oh odd
    const int b2 = L - S1_END;
    const int ohb = b2 % 3; const int rest = b2 / 3;
    const int dd = rest % 24; const int f0 = rest / 24;
    const int od = 2 * dd;
    const int t = tid % 12, yy = tid / 12;
    const int row = ohb * 16 + yy; if (row >= 47) return;
    const int oh = 2 * row + 1;
    conv_body<1, 2, 8>(x, w, out, f0, od, oh, t, cob);
  } else {                                     // od even, oh even
    const int b2 = L - S2_END;
    const int ohb = b2 % 3; const int rest = b2 / 3;
    const int dd = rest % 24; const int f0 = rest / 24;
    const int od = 2 * dd;
    const int t = tid % 12, yy = tid / 12;
    const int oh = 2 * (ohb * 16 + yy);
    conv_body<1, 1, 8>(x, w, out, f0, od, oh, t, cob);
  }
}
}  // namespace

extern "C" void kernel_launch(void* const* d_in, const int* in_sizes, int n_in,
                              void* d_out, int out_size, void* d_ws, size_t ws_size,
                              hipStream_t stream) {
  const float* x = (const float*)d_in[0];
  const float* w = (const float*)d_in[1];
  float* out = (float*)d_out;
  hipLaunchKernelGGL(convt4d_kernel, dim3(NWG), dim3(192), 0, stream, x, w, out);
}